// Round 14
// baseline (130.480 us; speedup 1.0000x reference)
//
#include <hip/hip_runtime.h>

#define NN 50000
#define NE 600000
#define CAP 64     // adjacency bucket capacity per node (Poisson(12) => safe)

typedef __attribute__((ext_vector_type(8))) short bf16x8;
typedef __attribute__((ext_vector_type(8))) unsigned short u16x8;
typedef __attribute__((ext_vector_type(4))) float f32x4;

__device__ __forceinline__ unsigned short f2bf(float f) {
    union { float f; unsigned int u; } v; v.f = f;
    unsigned int r = v.u + 0x7FFF + ((v.u >> 16) & 1);   // round-to-nearest-even
    return (unsigned short)(r >> 16);
}
__device__ __forceinline__ float bf2f(unsigned short u) {
    union { unsigned int u; float f; } v; v.u = ((unsigned int)u) << 16;
    return v.f;
}

// int64-vs-int32 edge buffer signature (wave-uniform, 6 cached loads)
__device__ __forceinline__ int edges_is64(const int* __restrict__ ei) {
    return ((ei[1] | ei[3] | ei[5] | ei[7] | ei[9] | ei[11]) == 0) ? 1 : 0;
}

// ---------------------------------------------------------------------------
// zero_prep: cnt := 0; x -> xb
#define XV   (NN * 128 / 4)          // 1,600,000 float4s
#define W1V  (128 * 256 / 4)         // 8192
#define W2V  (128 * 128 / 4)         // 4096
#define PB   ((XV + 255) / 256)
#define CB   ((NE + 255) / 256)
__global__ __launch_bounds__(256) void zero_prep_kernel(const float* __restrict__ x,
                                                        unsigned short* __restrict__ xb,
                                                        int* __restrict__ cnt) {
    int i = blockIdx.x * 256 + threadIdx.x;
    if (i < NN) cnt[i] = 0;
    if (i < XV) {
        float4 v = ((const float4*)x)[i];
        ushort4 o;
        o.x = f2bf(v.x); o.y = f2bf(v.y); o.z = f2bf(v.z); o.w = f2bf(v.w);
        ((ushort4*)xb)[i] = o;
    }
}

// ---------------------------------------------------------------------------
// fillb: bucketed adjacency build (atomic slots) + W bf16 conversion rides.
__global__ __launch_bounds__(256) void fillb_kernel(const int* __restrict__ ei,
                                                    const float* __restrict__ W1l,
                                                    const float* __restrict__ W1r,
                                                    const float* __restrict__ W2l,
                                                    const float* __restrict__ W2r,
                                                    unsigned short* __restrict__ Wb1,
                                                    unsigned short* __restrict__ Wb2,
                                                    int* __restrict__ cnt,
                                                    int* __restrict__ adj) {
    int is64 = edges_is64(ei);
    int e = blockIdx.x * 256 + threadIdx.x;
    if (e < NE) {
        int s, d;
        if (is64) { s = ei[2 * e]; d = ei[2 * (NE + e)]; }
        else      { s = ei[e];     d = ei[NE + e]; }
        int slot = atomicAdd(&cnt[d], 1);
        if (slot < CAP) adj[d * CAP + slot] = s;
    }
    int i = blockIdx.x * 256 + threadIdx.x;
    if (i < W1V + W2V) {
        const float* src;
        unsigned short* dst;
        if (i < W1V) {
            int j = i * 4;                     // elem index in Wb1 [128][256]
            int c = j >> 8, k = j & 255;
            src = (k < 128) ? (W1l + c * 128 + k) : (W1r + c * 128 + (k - 128));
            dst = Wb1 + j;
        } else {
            int j = (i - W1V) * 4;             // elem index in Wb2 [128][128]
            int c = j >> 7, k = j & 127;
            src = (c < 64) ? (W2l + c * 128 + k) : (W2r + (c - 64) * 128 + k);
            dst = Wb2 + j;
        }
        float4 v = *(const float4*)src;
        ushort4 o;
        o.x = f2bf(v.x); o.y = f2bf(v.y); o.z = f2bf(v.z); o.w = f2bf(v.w);
        *(ushort4*)dst = o;
    }
}

// ---------------------------------------------------------------------------
// Fused layer-1 aggregate + dual GEMM. 512 thr = 8 waves; 32-node tile.
//   Phase A: 32 nodes aggregated in PARALLEL (16 lanes/node, ushort8,
//            unroll-8) -> mean written bf16 into swizzled LDS sT[32][128].
//   Phase B: preload t1 A-frags from LDS -> regs; GEMM1 (K=256, x-half from
//            global xb) -> relu+bias -> h into same LDS -> GEMM2 (K=128)
//            -> grout[r][0..63]=g, [64..127]=rout (bf16).
// Wave layout phase B: wv = wr*4+wc; wave tile 16 rows x 32 cols.
__global__ __launch_bounds__(512) void fused_agg_mfma_kernel(
        const unsigned short* __restrict__ xb,
        const int* __restrict__ adj,
        const int* __restrict__ cnt,
        const unsigned short* __restrict__ Wb1,
        const float* __restrict__ b1,
        const unsigned short* __restrict__ Wb2,
        unsigned short* __restrict__ grout) {
    __shared__ unsigned short sT[32 * 128];   // 8 KB, 256 B rows, XOR-swizzled

    const int t = threadIdx.x;
    const int tile0 = blockIdx.x * 32;

    // ===== Phase A: parallel gather-mean into LDS =====
    {
        int nl = t >> 4;                  // local node 0..31
        int l = t & 15;                   // lane-slice (ushort8 = 16 B)
        int node = tile0 + nl;
        float a[8] = {};
        int deg = 0;
        if (node < NN) {
            int beg = node * CAP;
            deg = cnt[node];
            int dl = (deg < CAP) ? deg : CAP;
            const u16x8* fb = (const u16x8*)xb;   // row stride = 16
            int j = 0;
            for (; j + 8 <= dl; j += 8) {
                u16x8 v0 = fb[(size_t)adj[beg + j + 0] * 16 + l];
                u16x8 v1 = fb[(size_t)adj[beg + j + 1] * 16 + l];
                u16x8 v2 = fb[(size_t)adj[beg + j + 2] * 16 + l];
                u16x8 v3 = fb[(size_t)adj[beg + j + 3] * 16 + l];
                u16x8 v4 = fb[(size_t)adj[beg + j + 4] * 16 + l];
                u16x8 v5 = fb[(size_t)adj[beg + j + 5] * 16 + l];
                u16x8 v6 = fb[(size_t)adj[beg + j + 6] * 16 + l];
                u16x8 v7 = fb[(size_t)adj[beg + j + 7] * 16 + l];
#pragma unroll
                for (int q = 0; q < 8; ++q)
                    a[q] += ((bf2f(v0[q]) + bf2f(v1[q])) + (bf2f(v2[q]) + bf2f(v3[q])))
                          + ((bf2f(v4[q]) + bf2f(v5[q])) + (bf2f(v6[q]) + bf2f(v7[q])));
            }
            if (j + 4 <= dl) {
                u16x8 v0 = fb[(size_t)adj[beg + j + 0] * 16 + l];
                u16x8 v1 = fb[(size_t)adj[beg + j + 1] * 16 + l];
                u16x8 v2 = fb[(size_t)adj[beg + j + 2] * 16 + l];
                u16x8 v3 = fb[(size_t)adj[beg + j + 3] * 16 + l];
#pragma unroll
                for (int q = 0; q < 8; ++q)
                    a[q] += (bf2f(v0[q]) + bf2f(v1[q])) + (bf2f(v2[q]) + bf2f(v3[q]));
                j += 4;
            }
            for (; j < dl; ++j) {
                u16x8 v = fb[(size_t)adj[beg + j] * 16 + l];
#pragma unroll
                for (int q = 0; q < 8; ++q) a[q] += bf2f(v[q]);
            }
        }
        float inv = 1.0f / fmaxf((float)deg, 1.0f);
        u16x8 o;
#pragma unroll
        for (int q = 0; q < 8; ++q) o[q] = f2bf(a[q] * inv);
        // swizzled 16B store: row nl, byte col l*16
        unsigned int bo = nl * 256 + ((l * 16) ^ ((nl & 7) << 4));
        *(u16x8*)((char*)sT + bo) = o;
    }
    __syncthreads();

    // ===== Phase B =====
    const int lane = t & 63;
    const int wv = t >> 6;            // 0..7
    const int wr = wv >> 2;           // 0..1
    const int wc = wv & 3;            // 0..3
    const int l16 = lane & 15;
    const int khi = lane >> 4;        // 0..3
    const int lr = wr * 16 + l16;     // local row 0..31
    const int rowbase = tile0 + wr * 16;

    // preload t1-half A-fragments (ks = 0..3) from LDS into registers
    bf16x8 aL[4];
#pragma unroll
    for (int ks = 0; ks < 4; ++ks) {
        unsigned int bo = lr * 256 + ((ks * 64 + khi * 16) ^ ((lr & 7) << 4));
        aL[ks] = *(const bf16x8*)((const char*)sT + bo);
    }
    __syncthreads();    // all reads done; sT reusable for h

    // ---- GEMM1: K = 256 = [t1 (LDS regs) | xb (global)]
    f32x4 acc[2] = {};
#pragma unroll
    for (int ks = 0; ks < 8; ++ks) {
        bf16x8 a;
        if (ks < 4) {
            a = aL[ks];
        } else {
            int r = rowbase + l16;
            r = (r < NN) ? r : (NN - 1);      // clamp; stores are guarded
            int kk = (ks - 4) * 32 + khi * 8;
            a = *(const bf16x8*)(xb + (size_t)r * 128 + kk);
        }
#pragma unroll
        for (int ct = 0; ct < 2; ++ct) {
            int c = wc * 32 + ct * 16 + l16;
            bf16x8 b = *(const bf16x8*)(Wb1 + (size_t)c * 256 + ks * 32 + khi * 8);
            acc[ct] = __builtin_amdgcn_mfma_f32_16x16x32_bf16(a, b, acc[ct], 0, 0, 0);
        }
    }

    // ---- epilogue 1: relu+bias -> LDS h (bf16, swizzled)
#pragma unroll
    for (int j = 0; j < 4; ++j) {
        int hr = wr * 16 + khi * 4 + j;       // local row 0..31
#pragma unroll
        for (int ct = 0; ct < 2; ++ct) {
            int c = wc * 32 + ct * 16 + l16;
            float v = fmaxf(acc[ct][j] + b1[c], 0.f);
            unsigned int bo = hr * 256 + ((c * 2) ^ ((hr & 7) << 4));
            *(unsigned short*)((char*)sT + bo) = f2bf(v);
        }
    }
    __syncthreads();

    // ---- GEMM2: K = 128, A = sT (h, swizzled reads)
    f32x4 acc2[2] = {};
#pragma unroll
    for (int ks = 0; ks < 4; ++ks) {
        unsigned int bo = lr * 256 + ((ks * 64 + khi * 16) ^ ((lr & 7) << 4));
        bf16x8 a = *(const bf16x8*)((const char*)sT + bo);
#pragma unroll
        for (int ct = 0; ct < 2; ++ct) {
            int c = wc * 32 + ct * 16 + l16;
            bf16x8 b = *(const bf16x8*)(Wb2 + (size_t)c * 128 + ks * 32 + khi * 8);
            acc2[ct] = __builtin_amdgcn_mfma_f32_16x16x32_bf16(a, b, acc2[ct], 0, 0, 0);
        }
    }

    // ---- epilogue 2: grout[r][c] = bf16(acc2)
#pragma unroll
    for (int j = 0; j < 4; ++j) {
        int r = rowbase + khi * 4 + j;
        if (r < NN) {
#pragma unroll
            for (int ct = 0; ct < 2; ++ct) {
                int c = wc * 32 + ct * 16 + l16;
                grout[(size_t)r * 128 + c] = f2bf(acc2[ct][j]);
            }
        }
    }
}

// ---------------------------------------------------------------------------
// Layer-2 final: out[node][4l..4l+3] = mean_nbrs(g) + rout[node] + b2
// grout rows: 128 bf16 = [g 0..63 | rout 64..127]. 16 lanes/node (ushort4).
__global__ __launch_bounds__(256) void agg2_kernel(const unsigned short* __restrict__ grout,
                                                   const int* __restrict__ adj,
                                                   const int* __restrict__ cnt,
                                                   const float* __restrict__ b2,
                                                   float* __restrict__ out) {
    constexpr int LPN = 16;              // lanes per node (16 x 8B = g's 128B)
    int node = blockIdx.x * 16 + (threadIdx.x / LPN);
    int l = threadIdx.x & (LPN - 1);
    if (node >= NN) return;
    int beg = node * CAP;
    int deg = cnt[node];
    int dl = (deg < CAP) ? deg : CAP;
    const ushort4* fb = (const ushort4*)grout;  // row stride = 32 ushort4
    float a0 = 0.f, a1 = 0.f, a2 = 0.f, a3 = 0.f;
    int j = 0;
    for (; j + 8 <= dl; j += 8) {
        ushort4 v0 = fb[(size_t)adj[beg + j + 0] * 32 + l];
        ushort4 v1 = fb[(size_t)adj[beg + j + 1] * 32 + l];
        ushort4 v2 = fb[(size_t)adj[beg + j + 2] * 32 + l];
        ushort4 v3 = fb[(size_t)adj[beg + j + 3] * 32 + l];
        ushort4 v4 = fb[(size_t)adj[beg + j + 4] * 32 + l];
        ushort4 v5 = fb[(size_t)adj[beg + j + 5] * 32 + l];
        ushort4 v6 = fb[(size_t)adj[beg + j + 6] * 32 + l];
        ushort4 v7 = fb[(size_t)adj[beg + j + 7] * 32 + l];
        a0 += ((bf2f(v0.x) + bf2f(v1.x)) + (bf2f(v2.x) + bf2f(v3.x)))
            + ((bf2f(v4.x) + bf2f(v5.x)) + (bf2f(v6.x) + bf2f(v7.x)));
        a1 += ((bf2f(v0.y) + bf2f(v1.y)) + (bf2f(v2.y) + bf2f(v3.y)))
            + ((bf2f(v4.y) + bf2f(v5.y)) + (bf2f(v6.y) + bf2f(v7.y)));
        a2 += ((bf2f(v0.z) + bf2f(v1.z)) + (bf2f(v2.z) + bf2f(v3.z)))
            + ((bf2f(v4.z) + bf2f(v5.z)) + (bf2f(v6.z) + bf2f(v7.z)));
        a3 += ((bf2f(v0.w) + bf2f(v1.w)) + (bf2f(v2.w) + bf2f(v3.w)))
            + ((bf2f(v4.w) + bf2f(v5.w)) + (bf2f(v6.w) + bf2f(v7.w)));
    }
    if (j + 4 <= dl) {
        ushort4 v0 = fb[(size_t)adj[beg + j + 0] * 32 + l];
        ushort4 v1 = fb[(size_t)adj[beg + j + 1] * 32 + l];
        ushort4 v2 = fb[(size_t)adj[beg + j + 2] * 32 + l];
        ushort4 v3 = fb[(size_t)adj[beg + j + 3] * 32 + l];
        a0 += (bf2f(v0.x) + bf2f(v1.x)) + (bf2f(v2.x) + bf2f(v3.x));
        a1 += (bf2f(v0.y) + bf2f(v1.y)) + (bf2f(v2.y) + bf2f(v3.y));
        a2 += (bf2f(v0.z) + bf2f(v1.z)) + (bf2f(v2.z) + bf2f(v3.z));
        a3 += (bf2f(v0.w) + bf2f(v1.w)) + (bf2f(v2.w) + bf2f(v3.w));
        j += 4;
    }
    for (; j < dl; ++j) {
        ushort4 v = fb[(size_t)adj[beg + j] * 32 + l];
        a0 += bf2f(v.x); a1 += bf2f(v.y); a2 += bf2f(v.z); a3 += bf2f(v.w);
    }
    float inv = 1.0f / fmaxf((float)deg, 1.0f);
    ushort4 rv = fb[(size_t)node * 32 + 16 + l];      // rout half
    float4 o;
    o.x = a0 * inv + bf2f(rv.x) + b2[4 * l + 0];
    o.y = a1 * inv + bf2f(rv.y) + b2[4 * l + 1];
    o.z = a2 * inv + bf2f(rv.z) + b2[4 * l + 2];
    o.w = a3 * inv + bf2f(rv.w) + b2[4 * l + 3];
    *(float4*)(out + (size_t)node * 64 + 4 * l) = o;
}

// ---------------------------------------------------------------------------
extern "C" void kernel_launch(void* const* d_in, const int* in_sizes, int n_in,
                              void* d_out, int out_size, void* d_ws, size_t ws_size,
                              hipStream_t stream) {
    const float* x   = (const float*)d_in[0];
    const int*   ei  = (const int*)d_in[1];
    const float* W1l = (const float*)d_in[2];
    const float* b1  = (const float*)d_in[3];
    const float* W1r = (const float*)d_in[4];
    const float* W2l = (const float*)d_in[5];
    const float* b2  = (const float*)d_in[6];
    const float* W2r = (const float*)d_in[7];
    float* out = (float*)d_out;

    char* ws = (char*)d_ws;
    int* cnt = (int*)(ws + 64);                        // NN
    int* adj = cnt + NN;                               // NN*CAP (bucketed)
    unsigned short* xb    = (unsigned short*)(adj + (size_t)NN * CAP);  // NN*128
    unsigned short* grout = xb + (size_t)NN * 128;         // NN*128
    unsigned short* Wb1   = grout + (size_t)NN * 128;      // 128*256
    unsigned short* Wb2   = Wb1 + 128 * 256;               // 128*128

    size_t needed = 64 + (size_t)NN * 4 + (size_t)NN * CAP * 4
                  + ((size_t)NN * 128 * 2 + 128 * 256 + 128 * 128) * 2;
    if (ws_size < needed) return;    // fail loudly vs corrupt

    // 1. zero cnt + x -> bf16
    zero_prep_kernel<<<PB, 256, 0, stream>>>(x, xb, cnt);
    // 2. bucketed adjacency + W -> bf16
    fillb_kernel<<<CB, 256, 0, stream>>>(ei, W1l, W1r, W2l, W2r, Wb1, Wb2,
                                         cnt, adj);
    // 3. fused: agg1 (LDS) + dual GEMM -> grout = [g | rout]
    fused_agg_mfma_kernel<<<(NN + 31) / 32, 512, 0, stream>>>(
        xb, adj, cnt, Wb1, b1, Wb2, grout);
    // 4. layer 2 final: out = mean(g) + rout + b2
    agg2_kernel<<<(NN + 15) / 16, 256, 0, stream>>>(grout, adj, cnt, b2, out);
}

// Round 15
// 119.523 us; speedup vs baseline: 1.0917x; 1.0917x over previous
//
#include <hip/hip_runtime.h>

#define NN 50000
#define NE 600000
#define CAP 64     // adjacency bucket capacity per node (Poisson(12) => safe)

typedef __attribute__((ext_vector_type(8))) short bf16x8;
typedef __attribute__((ext_vector_type(8))) unsigned short u16x8;
typedef __attribute__((ext_vector_type(4))) float f32x4;

__device__ __forceinline__ unsigned short f2bf(float f) {
    union { float f; unsigned int u; } v; v.f = f;
    unsigned int r = v.u + 0x7FFF + ((v.u >> 16) & 1);   // round-to-nearest-even
    return (unsigned short)(r >> 16);
}
__device__ __forceinline__ float bf2f(unsigned short u) {
    union { unsigned int u; float f; } v; v.u = ((unsigned int)u) << 16;
    return v.f;
}

// int64-vs-int32 edge buffer signature (wave-uniform, 6 cached loads)
__device__ __forceinline__ int edges_is64(const int* __restrict__ ei) {
    return ((ei[1] | ei[3] | ei[5] | ei[7] | ei[9] | ei[11]) == 0) ? 1 : 0;
}

// ---------------------------------------------------------------------------
// zero_prep: cnt := 0; x -> xb  (W conversion rides in fillb)
#define XV   (NN * 128 / 4)          // 1,600,000 float4s
#define W1V  (128 * 256 / 4)         // 8192
#define W2V  (128 * 128 / 4)         // 4096
#define PB   ((XV + 255) / 256)                  // 6250 blocks
#define CB   ((NE + 255) / 256)                  // 2344 blocks
__global__ __launch_bounds__(256) void zero_prep_kernel(const float* __restrict__ x,
                                                        unsigned short* __restrict__ xb,
                                                        int* __restrict__ cnt) {
    int i = blockIdx.x * 256 + threadIdx.x;
    if (i < NN) cnt[i] = 0;
    if (i < XV) {
        float4 v = ((const float4*)x)[i];
        ushort4 o;
        o.x = f2bf(v.x); o.y = f2bf(v.y); o.z = f2bf(v.z); o.w = f2bf(v.w);
        ((ushort4*)xb)[i] = o;
    }
}

// ---------------------------------------------------------------------------
// fillb: bucketed adjacency build (atomic slots) + W bf16 conversion rides
// along (independent work, complementary pipes).
__global__ __launch_bounds__(256) void fillb_kernel(const int* __restrict__ ei,
                                                    const float* __restrict__ W1l,
                                                    const float* __restrict__ W1r,
                                                    const float* __restrict__ W2l,
                                                    const float* __restrict__ W2r,
                                                    unsigned short* __restrict__ Wb1,
                                                    unsigned short* __restrict__ Wb2,
                                                    int* __restrict__ cnt,
                                                    int* __restrict__ adj) {
    int is64 = edges_is64(ei);
    int e = blockIdx.x * 256 + threadIdx.x;
    if (e < NE) {
        int s, d;
        if (is64) { s = ei[2 * e]; d = ei[2 * (NE + e)]; }
        else      { s = ei[e];     d = ei[NE + e]; }
        int slot = atomicAdd(&cnt[d], 1);
        if (slot < CAP) adj[d * CAP + slot] = s;
    }
    // W conversion: 12288 float4s spread over the first 12288 threads
    int i = blockIdx.x * 256 + threadIdx.x;
    if (i < W1V + W2V) {
        const float* src;
        unsigned short* dst;
        if (i < W1V) {
            int j = i * 4;                     // elem index in Wb1 [128][256]
            int c = j >> 8, k = j & 255;
            src = (k < 128) ? (W1l + c * 128 + k) : (W1r + c * 128 + (k - 128));
            dst = Wb1 + j;
        } else {
            int j = (i - W1V) * 4;             // elem index in Wb2 [128][128]
            int c = j >> 7, k = j & 127;
            src = (c < 64) ? (W2l + c * 128 + k) : (W2r + (c - 64) * 128 + k);
            dst = Wb2 + j;
        }
        float4 v = *(const float4*)src;
        ushort4 o;
        o.x = f2bf(v.x); o.y = f2bf(v.y); o.z = f2bf(v.z); o.w = f2bf(v.w);
        *(ushort4*)dst = o;
    }
}

// ---------------------------------------------------------------------------
// Layer-1 gather-mean: bf16 features, f32 accumulate, ushort8 (16 B) / lane.
// 16 lanes/node, 4 nodes/wave. Unroll-8 => 8 outstanding 16B loads per lane.
__global__ __launch_bounds__(256) void agg1_kernel(const unsigned short* __restrict__ feat,
                                                   const int* __restrict__ adj,
                                                   const int* __restrict__ cnt,
                                                   unsigned short* __restrict__ o16) {
    constexpr int LPN = 16;              // lanes per node (16 x 16B = 256B row)
    int node = blockIdx.x * 16 + (threadIdx.x / LPN);
    int l = threadIdx.x & (LPN - 1);
    if (node >= NN) return;
    int beg = node * CAP;
    int deg = cnt[node];
    int dl = (deg < CAP) ? deg : CAP;
    const u16x8* fb = (const u16x8*)feat;       // row stride = 16
    float a[8] = {};
    int j = 0;
    for (; j + 8 <= dl; j += 8) {
        u16x8 v0 = fb[(size_t)adj[beg + j + 0] * LPN + l];
        u16x8 v1 = fb[(size_t)adj[beg + j + 1] * LPN + l];
        u16x8 v2 = fb[(size_t)adj[beg + j + 2] * LPN + l];
        u16x8 v3 = fb[(size_t)adj[beg + j + 3] * LPN + l];
        u16x8 v4 = fb[(size_t)adj[beg + j + 4] * LPN + l];
        u16x8 v5 = fb[(size_t)adj[beg + j + 5] * LPN + l];
        u16x8 v6 = fb[(size_t)adj[beg + j + 6] * LPN + l];
        u16x8 v7 = fb[(size_t)adj[beg + j + 7] * LPN + l];
#pragma unroll
        for (int q = 0; q < 8; ++q)
            a[q] += ((bf2f(v0[q]) + bf2f(v1[q])) + (bf2f(v2[q]) + bf2f(v3[q])))
                  + ((bf2f(v4[q]) + bf2f(v5[q])) + (bf2f(v6[q]) + bf2f(v7[q])));
    }
    if (j + 4 <= dl) {
        u16x8 v0 = fb[(size_t)adj[beg + j + 0] * LPN + l];
        u16x8 v1 = fb[(size_t)adj[beg + j + 1] * LPN + l];
        u16x8 v2 = fb[(size_t)adj[beg + j + 2] * LPN + l];
        u16x8 v3 = fb[(size_t)adj[beg + j + 3] * LPN + l];
#pragma unroll
        for (int q = 0; q < 8; ++q)
            a[q] += (bf2f(v0[q]) + bf2f(v1[q])) + (bf2f(v2[q]) + bf2f(v3[q]));
        j += 4;
    }
    for (; j < dl; ++j) {
        u16x8 v = fb[(size_t)adj[beg + j] * LPN + l];
#pragma unroll
        for (int q = 0; q < 8; ++q) a[q] += bf2f(v[q]);
    }
    float inv = 1.0f / fmaxf((float)deg, 1.0f);
    u16x8 o;
#pragma unroll
    for (int q = 0; q < 8; ++q) o[q] = f2bf(a[q] * inv);
    ((u16x8*)o16)[(size_t)node * LPN + l] = o;
}

// ---------------------------------------------------------------------------
// Fused dual GEMM per 64-row block (256 thr = 4 waves, 2x2; wave = 32r x 64c):
//   GEMM1: h = relu([t1b | xb] @ Wb1.T + b1)   (K=256) -> LDS tile (swizzled)
//   GEMM2: grout = h @ Wb2.T (K=128): cols 0-63 = g, 64-127 = rout, all bf16
__global__ __launch_bounds__(256) void mfma12_kernel(const unsigned short* __restrict__ t1b,
                                                     const unsigned short* __restrict__ xb,
                                                     const unsigned short* __restrict__ Wb1,
                                                     const float* __restrict__ b1,
                                                     const unsigned short* __restrict__ Wb2,
                                                     unsigned short* __restrict__ grout) {
    __shared__ unsigned short sH[64 * 128];   // 16 KB, 256 B rows, XOR-swizzled

    const int t = threadIdx.x;
    const int lane = t & 63;
    const int wv = t >> 6;
    const int wr = wv >> 1, wc = wv & 1;
    const int rowbase = blockIdx.x * 64 + wr * 32;
    const int colbase = wc * 64;
    const int l16 = lane & 15;
    const int khi = lane >> 4;        // 0..3

    // ---- GEMM1: K = 256 = [t1b 128 | xb 128]
    f32x4 acc[2][4] = {};
#pragma unroll
    for (int ks = 0; ks < 8; ++ks) {
        bf16x8 a[2];
#pragma unroll
        for (int rt = 0; rt < 2; ++rt) {
            int r = rowbase + rt * 16 + l16;
            r = (r < NN) ? r : (NN - 1);          // clamp; stores are guarded
            const unsigned short* src = (ks < 4) ? t1b : xb;
            int kk = (ks & 3) * 32 + khi * 8;
            a[rt] = *(const bf16x8*)(src + (size_t)r * 128 + kk);
        }
        bf16x8 b[4];
#pragma unroll
        for (int ct = 0; ct < 4; ++ct) {
            int c = colbase + ct * 16 + l16;
            b[ct] = *(const bf16x8*)(Wb1 + (size_t)c * 256 + ks * 32 + khi * 8);
        }
#pragma unroll
        for (int rt = 0; rt < 2; ++rt)
#pragma unroll
            for (int ct = 0; ct < 4; ++ct)
                acc[rt][ct] = __builtin_amdgcn_mfma_f32_16x16x32_bf16(
                    a[rt], b[ct], acc[rt][ct], 0, 0, 0);
    }

    // ---- epilogue 1: relu+bias -> LDS (bf16, swizzled). Covers ALL 64 rows.
#pragma unroll
    for (int rt = 0; rt < 2; ++rt) {
#pragma unroll
        for (int j = 0; j < 4; ++j) {
            int lr = wr * 32 + rt * 16 + khi * 4 + j;     // local row 0..63
#pragma unroll
            for (int ct = 0; ct < 4; ++ct) {
                int c = colbase + ct * 16 + l16;
                float v = fmaxf(acc[rt][ct][j] + b1[c], 0.f);
                unsigned int bo = lr * 256 + ((c * 2) ^ ((lr & 7) << 4));
                *(unsigned short*)((char*)sH + bo) = f2bf(v);
            }
        }
    }
    __syncthreads();

    // ---- GEMM2: K = 128, A = sH (swizzled reads)
    f32x4 acc2[2][4] = {};
#pragma unroll
    for (int ks = 0; ks < 4; ++ks) {
        bf16x8 a[2];
#pragma unroll
        for (int rt = 0; rt < 2; ++rt) {
            int lr = wr * 32 + rt * 16 + l16;
            unsigned int bo = lr * 256 + ((ks * 64 + khi * 16) ^ ((lr & 7) << 4));
            a[rt] = *(const bf16x8*)((const char*)sH + bo);
        }
        bf16x8 b[4];
#pragma unroll
        for (int ct = 0; ct < 4; ++ct) {
            int c = colbase + ct * 16 + l16;
            b[ct] = *(const bf16x8*)(Wb2 + (size_t)c * 128 + ks * 32 + khi * 8);
        }
#pragma unroll
        for (int rt = 0; rt < 2; ++rt)
#pragma unroll
            for (int ct = 0; ct < 4; ++ct)
                acc2[rt][ct] = __builtin_amdgcn_mfma_f32_16x16x32_bf16(
                    a[rt], b[ct], acc2[rt][ct], 0, 0, 0);
    }

    // ---- epilogue 2: grout[r][c] = bf16(acc2)
#pragma unroll
    for (int rt = 0; rt < 2; ++rt) {
#pragma unroll
        for (int j = 0; j < 4; ++j) {
            int r = rowbase + rt * 16 + khi * 4 + j;
            if (r < NN) {
#pragma unroll
                for (int ct = 0; ct < 4; ++ct) {
                    int c = colbase + ct * 16 + l16;
                    grout[(size_t)r * 128 + c] = f2bf(acc2[rt][ct][j]);
                }
            }
        }
    }
}

// ---------------------------------------------------------------------------
// Layer-2 final: out[node][4l..4l+3] = mean_nbrs(g) + rout[node] + b2
// grout rows: 128 bf16 = [g 0..63 | rout 64..127]. 16 lanes/node (ushort4).
__global__ __launch_bounds__(256) void agg2_kernel(const unsigned short* __restrict__ grout,
                                                   const int* __restrict__ adj,
                                                   const int* __restrict__ cnt,
                                                   const float* __restrict__ b2,
                                                   float* __restrict__ out) {
    constexpr int LPN = 16;              // lanes per node (16 x 8B = g's 128B)
    int node = blockIdx.x * 16 + (threadIdx.x / LPN);
    int l = threadIdx.x & (LPN - 1);
    if (node >= NN) return;
    int beg = node * CAP;
    int deg = cnt[node];
    int dl = (deg < CAP) ? deg : CAP;
    const ushort4* fb = (const ushort4*)grout;  // row stride = 32 ushort4
    float a0 = 0.f, a1 = 0.f, a2 = 0.f, a3 = 0.f;
    int j = 0;
    for (; j + 8 <= dl; j += 8) {
        ushort4 v0 = fb[(size_t)adj[beg + j + 0] * 32 + l];
        ushort4 v1 = fb[(size_t)adj[beg + j + 1] * 32 + l];
        ushort4 v2 = fb[(size_t)adj[beg + j + 2] * 32 + l];
        ushort4 v3 = fb[(size_t)adj[beg + j + 3] * 32 + l];
        ushort4 v4 = fb[(size_t)adj[beg + j + 4] * 32 + l];
        ushort4 v5 = fb[(size_t)adj[beg + j + 5] * 32 + l];
        ushort4 v6 = fb[(size_t)adj[beg + j + 6] * 32 + l];
        ushort4 v7 = fb[(size_t)adj[beg + j + 7] * 32 + l];
        a0 += ((bf2f(v0.x) + bf2f(v1.x)) + (bf2f(v2.x) + bf2f(v3.x)))
            + ((bf2f(v4.x) + bf2f(v5.x)) + (bf2f(v6.x) + bf2f(v7.x)));
        a1 += ((bf2f(v0.y) + bf2f(v1.y)) + (bf2f(v2.y) + bf2f(v3.y)))
            + ((bf2f(v4.y) + bf2f(v5.y)) + (bf2f(v6.y) + bf2f(v7.y)));
        a2 += ((bf2f(v0.z) + bf2f(v1.z)) + (bf2f(v2.z) + bf2f(v3.z)))
            + ((bf2f(v4.z) + bf2f(v5.z)) + (bf2f(v6.z) + bf2f(v7.z)));
        a3 += ((bf2f(v0.w) + bf2f(v1.w)) + (bf2f(v2.w) + bf2f(v3.w)))
            + ((bf2f(v4.w) + bf2f(v5.w)) + (bf2f(v6.w) + bf2f(v7.w)));
    }
    if (j + 4 <= dl) {
        ushort4 v0 = fb[(size_t)adj[beg + j + 0] * 32 + l];
        ushort4 v1 = fb[(size_t)adj[beg + j + 1] * 32 + l];
        ushort4 v2 = fb[(size_t)adj[beg + j + 2] * 32 + l];
        ushort4 v3 = fb[(size_t)adj[beg + j + 3] * 32 + l];
        a0 += (bf2f(v0.x) + bf2f(v1.x)) + (bf2f(v2.x) + bf2f(v3.x));
        a1 += (bf2f(v0.y) + bf2f(v1.y)) + (bf2f(v2.y) + bf2f(v3.y));
        a2 += (bf2f(v0.z) + bf2f(v1.z)) + (bf2f(v2.z) + bf2f(v3.z));
        a3 += (bf2f(v0.w) + bf2f(v1.w)) + (bf2f(v2.w) + bf2f(v3.w));
        j += 4;
    }
    for (; j < dl; ++j) {
        ushort4 v = fb[(size_t)adj[beg + j] * 32 + l];
        a0 += bf2f(v.x); a1 += bf2f(v.y); a2 += bf2f(v.z); a3 += bf2f(v.w);
    }
    float inv = 1.0f / fmaxf((float)deg, 1.0f);
    ushort4 rv = fb[(size_t)node * 32 + 16 + l];      // rout half
    float4 o;
    o.x = a0 * inv + bf2f(rv.x) + b2[4 * l + 0];
    o.y = a1 * inv + bf2f(rv.y) + b2[4 * l + 1];
    o.z = a2 * inv + bf2f(rv.z) + b2[4 * l + 2];
    o.w = a3 * inv + bf2f(rv.w) + b2[4 * l + 3];
    *(float4*)(out + (size_t)node * 64 + 4 * l) = o;
}

// ---------------------------------------------------------------------------
extern "C" void kernel_launch(void* const* d_in, const int* in_sizes, int n_in,
                              void* d_out, int out_size, void* d_ws, size_t ws_size,
                              hipStream_t stream) {
    const float* x   = (const float*)d_in[0];
    const int*   ei  = (const int*)d_in[1];
    const float* W1l = (const float*)d_in[2];
    const float* b1  = (const float*)d_in[3];
    const float* W1r = (const float*)d_in[4];
    const float* W2l = (const float*)d_in[5];
    const float* b2  = (const float*)d_in[6];
    const float* W2r = (const float*)d_in[7];
    float* out = (float*)d_out;

    char* ws = (char*)d_ws;
    int* cnt = (int*)(ws + 64);                        // NN
    int* adj = cnt + NN;                               // NN*CAP (bucketed)
    unsigned short* xb    = (unsigned short*)(adj + (size_t)NN * CAP);  // NN*128
    unsigned short* t1b   = xb + (size_t)NN * 128;         // NN*128
    unsigned short* grout = t1b + (size_t)NN * 128;        // NN*128
    unsigned short* Wb1   = grout + (size_t)NN * 128;      // 128*256
    unsigned short* Wb2   = Wb1 + 128 * 256;               // 128*128

    size_t needed = 64 + (size_t)NN * 4 + (size_t)NN * CAP * 4
                  + ((size_t)NN * 128 * 3 + 128 * 256 + 128 * 128) * 2;
    if (ws_size < needed) return;    // fail loudly vs corrupt

    // 1. zero cnt + x -> bf16
    zero_prep_kernel<<<PB, 256, 0, stream>>>(x, xb, cnt);
    // 2. bucketed adjacency + W -> bf16
    fillb_kernel<<<CB, 256, 0, stream>>>(ei, W1l, W1r, W2l, W2r, Wb1, Wb2,
                                         cnt, adj);
    // 3. layer 1 aggregate: gather-mean(xb) -> t1b
    agg1_kernel<<<(NN + 15) / 16, 256, 0, stream>>>(xb, adj, cnt, t1b);
    // 4. fused GEMMs: h (LDS-only) -> grout = [g | rout] (bf16)
    mfma12_kernel<<<(NN + 63) / 64, 256, 0, stream>>>(t1b, xb, Wb1, b1, Wb2,
                                                      grout);
    // 5. layer 2 final: out = mean(g) + rout + b2
    agg2_kernel<<<(NN + 15) / 16, 256, 0, stream>>>(grout, adj, cnt, b2, out);
}